// Round 6
// baseline (607.234 us; speedup 1.0000x reference)
//
#include <hip/hip_runtime.h>

#define N_NODES 100000
#define E_EDGES 600000
#define LATDIM 128
#define HEAD 4
#define HDIM 32

#define SCAN_CHUNK 1024
#define SCAN_NB ((N_NODES + SCAN_CHUNK - 1) / SCAN_CHUNK)   // 98

__device__ __forceinline__ unsigned f32_to_bf16_rne(float x) {
    unsigned u = __float_as_uint(x);
    u += 0x7fffu + ((u >> 16) & 1u);   // round to nearest even
    return u >> 16;
}

// ---------------------------------------------------------------------------
// Kernel A: fused per-node Q/K/V transform, weights staged through LDS.
//   Q written f32; K,V packed as bf16 pair into one uint per (node, dim).
// Per pass: 4 k-tiles of 32; wbuf (16 KB) staged cooperatively; inner chunk
// = 4 w-float4 LDS reads + 8 e-float4 LDS broadcasts + 128 FMAs.
// ---------------------------------------------------------------------------
__global__ __launch_bounds__(256) void qkv_kernel(
    const float* __restrict__ embeds,
    const float* __restrict__ qT,
    const float* __restrict__ kT,
    const float* __restrict__ vT,
    float* __restrict__ Q, unsigned* __restrict__ KV)
{
    __shared__ float smem[64][128];   // 32 KiB embeds tile
    __shared__ float wbuf[32][128];   // 16 KiB weight k-tile
    const int rowBase = blockIdx.x * 64;
    const int tid = threadIdx.x;

    for (int i = tid; i < 64 * 32; i += 256) {   // 2048 float4
        int r  = i >> 5;
        int c4 = i & 31;
        int gr = rowBase + r;
        float4 val = make_float4(0.f, 0.f, 0.f, 0.f);
        if (gr < N_NODES) val = ((const float4*)embeds)[gr * 32 + c4];
        ((float4*)&smem[r][0])[c4] = val;
    }
    __syncthreads();

    const int cg = tid & 31;      // col group (4 cols)
    const int rg = tid >> 5;      // row group (8 rows)

    float4 acc[8];
    float4 kacc[8];

    const float* Ws[3] = {qT, kT, vT};

    for (int w = 0; w < 3; ++w) {
        const float4* Wf4 = (const float4*)Ws[w];
        float4* dst = (w == 1) ? kacc : acc;
        #pragma unroll
        for (int i = 0; i < 8; ++i) dst[i] = make_float4(0.f, 0.f, 0.f, 0.f);

        for (int kt = 0; kt < 4; ++kt) {
            __syncthreads();   // protect wbuf from previous tile's readers
            // stage W[kt*32 .. kt*32+31][0:128]: 1024 float4, 4 per thread
            #pragma unroll
            for (int j = 0; j < 4; ++j) {
                int idx = tid + j * 256;          // 0..1023
                int r  = idx >> 5;                // 0..31
                int c4 = idx & 31;
                ((float4*)&wbuf[r][0])[c4] = Wf4[(kt * 32 + r) * 32 + c4];
            }
            __syncthreads();

            #pragma unroll
            for (int k4 = 0; k4 < 8; ++k4) {
                float4 w0 = *((const float4*)&wbuf[k4 * 4 + 0][cg * 4]);
                float4 w1 = *((const float4*)&wbuf[k4 * 4 + 1][cg * 4]);
                float4 w2 = *((const float4*)&wbuf[k4 * 4 + 2][cg * 4]);
                float4 w3 = *((const float4*)&wbuf[k4 * 4 + 3][cg * 4]);
                #pragma unroll
                for (int i = 0; i < 8; ++i) {
                    float4 e = *((const float4*)&smem[rg * 8 + i][kt * 32 + k4 * 4]);
                    dst[i].x += e.x * w0.x + e.y * w1.x + e.z * w2.x + e.w * w3.x;
                    dst[i].y += e.x * w0.y + e.y * w1.y + e.z * w2.y + e.w * w3.y;
                    dst[i].z += e.x * w0.z + e.y * w1.z + e.z * w2.z + e.w * w3.z;
                    dst[i].w += e.x * w0.w + e.y * w1.w + e.z * w2.w + e.w * w3.w;
                }
            }
        }

        if (w == 0) {
            // write Q (f32)
            #pragma unroll
            for (int i = 0; i < 8; ++i) {
                int gr = rowBase + rg * 8 + i;
                if (gr < N_NODES)
                    ((float4*)(Q + (size_t)gr * 128))[cg] = acc[i];
            }
        }
    }

    // pack (k,v) -> uint per dim
    #pragma unroll
    for (int i = 0; i < 8; ++i) {
        int gr = rowBase + rg * 8 + i;
        if (gr < N_NODES) {
            uint4 p;
            p.x = f32_to_bf16_rne(kacc[i].x) | (f32_to_bf16_rne(acc[i].x) << 16);
            p.y = f32_to_bf16_rne(kacc[i].y) | (f32_to_bf16_rne(acc[i].y) << 16);
            p.z = f32_to_bf16_rne(kacc[i].z) | (f32_to_bf16_rne(acc[i].z) << 16);
            p.w = f32_to_bf16_rne(kacc[i].w) | (f32_to_bf16_rne(acc[i].w) << 16);
            ((uint4*)(KV + (size_t)gr * 128))[cg] = p;
        }
    }
}

// ---------------------------------------------------------------------------
// CSR build: histogram -> exclusive scan -> scatter (stores COLS directly)
// ---------------------------------------------------------------------------
__global__ __launch_bounds__(256) void hist_kernel(
    const int* __restrict__ rows, int* __restrict__ counts)
{
    int e = blockIdx.x * 256 + threadIdx.x;
    if (e < E_EDGES) atomicAdd(&counts[rows[e]], 1);
}

__global__ __launch_bounds__(256) void scan1_kernel(
    const int* __restrict__ counts, int* __restrict__ starts,
    int* __restrict__ blockSums)
{
    __shared__ int s[256];
    int b = blockIdx.x, t = threadIdx.x;
    int base = b * SCAN_CHUNK + t * 4;
    int v0 = (base + 0 < N_NODES) ? counts[base + 0] : 0;
    int v1 = (base + 1 < N_NODES) ? counts[base + 1] : 0;
    int v2 = (base + 2 < N_NODES) ? counts[base + 2] : 0;
    int v3 = (base + 3 < N_NODES) ? counts[base + 3] : 0;
    int local = v0 + v1 + v2 + v3;
    s[t] = local;
    __syncthreads();
    for (int off = 1; off < 256; off <<= 1) {
        int x = (t >= off) ? s[t - off] : 0;
        __syncthreads();
        s[t] += x;
        __syncthreads();
    }
    int incl = s[t];
    int excl = incl - local;
    if (base + 0 < N_NODES) starts[base + 0] = excl;
    if (base + 1 < N_NODES) starts[base + 1] = excl + v0;
    if (base + 2 < N_NODES) starts[base + 2] = excl + v0 + v1;
    if (base + 3 < N_NODES) starts[base + 3] = excl + v0 + v1 + v2;
    if (t == 255) blockSums[b] = incl;
}

__global__ __launch_bounds__(128) void scan2_kernel(int* __restrict__ blockSums)
{
    __shared__ int s[128];
    int t = threadIdx.x;
    int v = (t < SCAN_NB) ? blockSums[t] : 0;
    s[t] = v;
    __syncthreads();
    for (int off = 1; off < 128; off <<= 1) {
        int x = (t >= off) ? s[t - off] : 0;
        __syncthreads();
        s[t] += x;
        __syncthreads();
    }
    if (t < SCAN_NB) blockSums[t] = s[t] - v;   // exclusive
}

__global__ __launch_bounds__(256) void scan3_kernel(
    int* __restrict__ starts, const int* __restrict__ blockSums,
    int* __restrict__ cursor)
{
    int i = blockIdx.x * 256 + threadIdx.x;
    if (i < N_NODES) {
        int v = starts[i] + blockSums[i >> 10];
        starts[i] = v;
        cursor[i] = v;
    }
}

__global__ __launch_bounds__(256) void scatter_kernel(
    const int* __restrict__ rows, const int* __restrict__ cols,
    int* __restrict__ cursor, int* __restrict__ csrCols)
{
    int e = blockIdx.x * 256 + threadIdx.x;
    if (e >= E_EDGES) return;
    int pos = atomicAdd(&cursor[rows[e]], 1);
    csrCols[pos] = cols[e];
}

// ---------------------------------------------------------------------------
// Kernel B: fused attention + aggregation, bf16-packed K/V, 2-edge unroll.
// ---------------------------------------------------------------------------
__global__ __launch_bounds__(256) void att_agg_kernel(
    const float* __restrict__ Q, const unsigned* __restrict__ KV,
    const float* __restrict__ filt,
    const int* __restrict__ starts, const int* __restrict__ counts,
    const int* __restrict__ csrCols,
    float* __restrict__ out)
{
    int t = threadIdx.x;
    int node = blockIdx.x * 2 + (t >> 7);
    if (node >= N_NODES) return;
    int d = t & 127;
    int h = d >> 5;

    float qd  = Q[(size_t)node * 128 + d];
    int   s   = starts[node];
    int   cnt = counts[node];

    float norm = 0.f, acc = 0.f;
    int i = 0;
    for (; i + 2 <= cnt; i += 2) {
        int c0 = csrCols[s + i];
        int c1 = csrCols[s + i + 1];
        unsigned kv0 = KV[(size_t)c0 * 128 + d];
        unsigned kv1 = KV[(size_t)c1 * 128 + d];
        float f0 = filt[(size_t)c0 * HEAD + h];
        float f1 = filt[(size_t)c1 * HEAD + h];
        float k0 = __uint_as_float(kv0 << 16);
        float v0 = __uint_as_float(kv0 & 0xffff0000u);
        float k1 = __uint_as_float(kv1 << 16);
        float v1 = __uint_as_float(kv1 & 0xffff0000u);

        float p0 = qd * k0;
        float p1 = qd * k1;
        p0 += __shfl_xor(p0, 1);   p1 += __shfl_xor(p1, 1);
        p0 += __shfl_xor(p0, 2);   p1 += __shfl_xor(p1, 2);
        p0 += __shfl_xor(p0, 4);   p1 += __shfl_xor(p1, 4);
        p0 += __shfl_xor(p0, 8);   p1 += __shfl_xor(p1, 8);
        p0 += __shfl_xor(p0, 16);  p1 += __shfl_xor(p1, 16);

        float w0 = __expf(fminf(fmaxf(p0, -10.f), 10.f) + f0);
        float w1 = __expf(fminf(fmaxf(p1, -10.f), 10.f) + f1);
        norm += w0 + w1;
        acc  += w0 * v0 + w1 * v1;
    }
    if (i < cnt) {
        int c0 = csrCols[s + i];
        unsigned kv0 = KV[(size_t)c0 * 128 + d];
        float f0 = filt[(size_t)c0 * HEAD + h];
        float k0 = __uint_as_float(kv0 << 16);
        float v0 = __uint_as_float(kv0 & 0xffff0000u);
        float p0 = qd * k0;
        p0 += __shfl_xor(p0, 1);
        p0 += __shfl_xor(p0, 2);
        p0 += __shfl_xor(p0, 4);
        p0 += __shfl_xor(p0, 8);
        p0 += __shfl_xor(p0, 16);
        float w0 = __expf(fminf(fmaxf(p0, -10.f), 10.f) + f0);
        norm += w0;
        acc  += w0 * v0;
    }
    out[(size_t)node * 128 + d] = acc / (norm + 1e-8f);
}

// ---------------------------------------------------------------------------
extern "C" void kernel_launch(void* const* d_in, const int* in_sizes, int n_in,
                              void* d_out, int out_size, void* d_ws, size_t ws_size,
                              hipStream_t stream) {
    const float* embeds = (const float*)d_in[0];
    const float* qT     = (const float*)d_in[1];
    const float* kT     = (const float*)d_in[2];
    const float* vT     = (const float*)d_in[3];
    const float* filt   = (const float*)d_in[4];
    const int*   rows   = (const int*)d_in[5];
    const int*   cols   = (const int*)d_in[6];
    float*       out    = (float*)d_out;

    // Workspace: Q: N*128 f32 | KV: N*128 u32 | counts,starts,cursor: N i32 |
    //            blockSums: 128 i32 | csrCols: E i32
    float*    Q  = (float*)d_ws;
    unsigned* KV = (unsigned*)(Q + (size_t)N_NODES * 128);
    int* counts    = (int*)(KV + (size_t)N_NODES * 128);
    int* starts    = counts + N_NODES;
    int* cursor    = starts + N_NODES;
    int* blockSums = cursor + N_NODES;
    int* csrCols   = blockSums + 128;

    hipMemsetAsync(counts, 0, sizeof(int) * N_NODES, stream);

    qkv_kernel<<<(N_NODES + 63) / 64, 256, 0, stream>>>(embeds, qT, kT, vT, Q, KV);

    hist_kernel<<<(E_EDGES + 255) / 256, 256, 0, stream>>>(rows, counts);
    scan1_kernel<<<SCAN_NB, 256, 0, stream>>>(counts, starts, blockSums);
    scan2_kernel<<<1, 128, 0, stream>>>(blockSums);
    scan3_kernel<<<(N_NODES + 255) / 256, 256, 0, stream>>>(starts, blockSums, cursor);
    scatter_kernel<<<(E_EDGES + 255) / 256, 256, 0, stream>>>(rows, cols, cursor, csrCols);

    att_agg_kernel<<<(N_NODES + 1) / 2, 256, 0, stream>>>(
        Q, KV, filt, starts, counts, csrCols, out);
}

// Round 7
// 460.836 us; speedup vs baseline: 1.3177x; 1.3177x over previous
//
#include <hip/hip_runtime.h>

#define N_NODES 100000
#define E_EDGES 600000
#define LATDIM 128
#define HEAD 4
#define HDIM 32

#define SCAN_CHUNK 1024
#define SCAN_NB ((N_NODES + SCAN_CHUNK - 1) / SCAN_CHUNK)   // 98

typedef __attribute__((ext_vector_type(8))) short bf16x8;   // 8 bf16 (4 VGPRs)
typedef __attribute__((ext_vector_type(4))) float f32x4;    // MFMA accumulator

__device__ __forceinline__ unsigned f32_to_bf16_rne(float x) {
    unsigned u = __float_as_uint(x);
    u += 0x7fffu + ((u >> 16) & 1u);   // round to nearest even
    return u >> 16;
}
__device__ __forceinline__ float bf16_bits_to_f32(unsigned h) {
    return __uint_as_float(h << 16);
}

// ---------------------------------------------------------------------------
// Prep: split each 128x128 weight into bf16 hi/lo, TRANSPOSED to [n][k]
// so MFMA B-fragments (k-consecutive per column n) are 16B vector loads.
// ---------------------------------------------------------------------------
__global__ __launch_bounds__(256) void wsplit_kernel(
    const float* __restrict__ qT, const float* __restrict__ kT,
    const float* __restrict__ vT,
    unsigned short* __restrict__ WtHi, unsigned short* __restrict__ WtLo)
{
    int idx = blockIdx.x * 256 + threadIdx.x;       // 3*128*32 = 12288
    if (idx >= 3 * 128 * 32) return;
    int w   = idx >> 12;          // /4096
    int rem = idx & 4095;
    int k   = rem >> 5;
    int n4  = rem & 31;
    const float* W = (w == 0) ? qT : (w == 1) ? kT : vT;
    float4 v = ((const float4*)W)[k * 32 + n4];
    float xs[4] = {v.x, v.y, v.z, v.w};
    #pragma unroll
    for (int c = 0; c < 4; ++c) {
        int n = n4 * 4 + c;
        unsigned h = f32_to_bf16_rne(xs[c]);
        float    r = xs[c] - bf16_bits_to_f32(h);
        unsigned l = f32_to_bf16_rne(r);
        WtHi[w * 16384 + n * 128 + k] = (unsigned short)h;
        WtLo[w * 16384 + n * 128 + k] = (unsigned short)l;
    }
}

// ---------------------------------------------------------------------------
// Kernel A: Q/K/V transform via split-bf16 MFMA (hi/lo -> ~f32 precision).
// Block: 256 thr = 4 waves, 64-row tile. Wave wv owns rows wv*16..+15,
// all 128 cols. A staged hi/lo in LDS (pad +8 bf16/row); B-frags read
// straight from L2-hot transposed weights. 3 MFMA per (tile,kc): hh+hl+lh.
// ---------------------------------------------------------------------------
__global__ __launch_bounds__(256) void qkv_kernel(
    const float* __restrict__ embeds,
    const unsigned short* __restrict__ WtHi,
    const unsigned short* __restrict__ WtLo,
    float* __restrict__ Q, unsigned* __restrict__ KV)
{
    __shared__ unsigned short Ahi[64 * 136];   // 17408 B
    __shared__ unsigned short Alo[64 * 136];   // 17408 B

    const int tid = threadIdx.x;
    const int rowBase = blockIdx.x * 64;

    // ---- stage embeds tile as hi/lo bf16 ----
    #pragma unroll
    for (int j = 0; j < 8; ++j) {
        int i  = tid + j * 256;       // 0..2047
        int r  = i >> 5;
        int c4 = i & 31;
        int gr = rowBase + r;
        float4 v = make_float4(0.f, 0.f, 0.f, 0.f);
        if (gr < N_NODES) v = ((const float4*)embeds)[gr * 32 + c4];
        float xs[4] = {v.x, v.y, v.z, v.w};
        unsigned h[4], l[4];
        #pragma unroll
        for (int c = 0; c < 4; ++c) {
            h[c] = f32_to_bf16_rne(xs[c]);
            l[c] = f32_to_bf16_rne(xs[c] - bf16_bits_to_f32(h[c]));
        }
        int base = r * 136 + c4 * 4;         // ushort index, even
        ((unsigned*)Ahi)[(base >> 1) + 0] = h[0] | (h[1] << 16);
        ((unsigned*)Ahi)[(base >> 1) + 1] = h[2] | (h[3] << 16);
        ((unsigned*)Alo)[(base >> 1) + 0] = l[0] | (l[1] << 16);
        ((unsigned*)Alo)[(base >> 1) + 1] = l[2] | (l[3] << 16);
    }
    __syncthreads();

    const int wv   = tid >> 6;           // wave 0..3
    const int lane = tid & 63;
    const int l15  = lane & 15;
    const int quad = lane >> 4;          // 0..3

    f32x4 kacc[8];
    f32x4 acc[8];

    for (int w = 0; w < 3; ++w) {
        const unsigned short* WH = WtHi + w * 16384;
        const unsigned short* WL = WtLo + w * 16384;
        #pragma unroll
        for (int nt = 0; nt < 8; ++nt) acc[nt] = (f32x4){0.f, 0.f, 0.f, 0.f};

        #pragma unroll
        for (int kc = 0; kc < 4; ++kc) {
            int k0 = kc * 32 + quad * 8;
            bf16x8 ah = *(const bf16x8*)&Ahi[(wv * 16 + l15) * 136 + k0];
            bf16x8 al = *(const bf16x8*)&Alo[(wv * 16 + l15) * 136 + k0];
            #pragma unroll
            for (int nt = 0; nt < 8; ++nt) {
                int n = nt * 16 + l15;
                bf16x8 bh = *(const bf16x8*)&WH[n * 128 + k0];
                bf16x8 bl = *(const bf16x8*)&WL[n * 128 + k0];
                acc[nt] = __builtin_amdgcn_mfma_f32_16x16x32_bf16(ah, bh, acc[nt], 0, 0, 0);
                acc[nt] = __builtin_amdgcn_mfma_f32_16x16x32_bf16(ah, bl, acc[nt], 0, 0, 0);
                acc[nt] = __builtin_amdgcn_mfma_f32_16x16x32_bf16(al, bh, acc[nt], 0, 0, 0);
            }
        }

        if (w == 0) {
            // write Q f32. C/D layout: row = quad*4 + r, col = l15.
            #pragma unroll
            for (int nt = 0; nt < 8; ++nt)
                #pragma unroll
                for (int r = 0; r < 4; ++r) {
                    int gr = rowBase + wv * 16 + quad * 4 + r;
                    if (gr < N_NODES)
                        Q[(size_t)gr * 128 + nt * 16 + l15] = acc[nt][r];
                }
        } else if (w == 1) {
            #pragma unroll
            for (int nt = 0; nt < 8; ++nt) kacc[nt] = acc[nt];
        } else {
            #pragma unroll
            for (int nt = 0; nt < 8; ++nt)
                #pragma unroll
                for (int r = 0; r < 4; ++r) {
                    int gr = rowBase + wv * 16 + quad * 4 + r;
                    if (gr < N_NODES) {
                        unsigned kv = f32_to_bf16_rne(kacc[nt][r]) |
                                      (f32_to_bf16_rne(acc[nt][r]) << 16);
                        KV[(size_t)gr * 128 + nt * 16 + l15] = kv;
                    }
                }
        }
    }
}

// ---------------------------------------------------------------------------
// CSR build: histogram -> exclusive scan -> scatter (stores COLS directly)
// ---------------------------------------------------------------------------
__global__ __launch_bounds__(256) void hist_kernel(
    const int* __restrict__ rows, int* __restrict__ counts)
{
    int e = blockIdx.x * 256 + threadIdx.x;
    if (e < E_EDGES) atomicAdd(&counts[rows[e]], 1);
}

__global__ __launch_bounds__(256) void scan1_kernel(
    const int* __restrict__ counts, int* __restrict__ starts,
    int* __restrict__ blockSums)
{
    __shared__ int s[256];
    int b = blockIdx.x, t = threadIdx.x;
    int base = b * SCAN_CHUNK + t * 4;
    int v0 = (base + 0 < N_NODES) ? counts[base + 0] : 0;
    int v1 = (base + 1 < N_NODES) ? counts[base + 1] : 0;
    int v2 = (base + 2 < N_NODES) ? counts[base + 2] : 0;
    int v3 = (base + 3 < N_NODES) ? counts[base + 3] : 0;
    int local = v0 + v1 + v2 + v3;
    s[t] = local;
    __syncthreads();
    for (int off = 1; off < 256; off <<= 1) {
        int x = (t >= off) ? s[t - off] : 0;
        __syncthreads();
        s[t] += x;
        __syncthreads();
    }
    int incl = s[t];
    int excl = incl - local;
    if (base + 0 < N_NODES) starts[base + 0] = excl;
    if (base + 1 < N_NODES) starts[base + 1] = excl + v0;
    if (base + 2 < N_NODES) starts[base + 2] = excl + v0 + v1;
    if (base + 3 < N_NODES) starts[base + 3] = excl + v0 + v1 + v2;
    if (t == 255) blockSums[b] = incl;
}

__global__ __launch_bounds__(128) void scan2_kernel(int* __restrict__ blockSums)
{
    __shared__ int s[128];
    int t = threadIdx.x;
    int v = (t < SCAN_NB) ? blockSums[t] : 0;
    s[t] = v;
    __syncthreads();
    for (int off = 1; off < 128; off <<= 1) {
        int x = (t >= off) ? s[t - off] : 0;
        __syncthreads();
        s[t] += x;
        __syncthreads();
    }
    if (t < SCAN_NB) blockSums[t] = s[t] - v;   // exclusive
}

__global__ __launch_bounds__(256) void scan3_kernel(
    int* __restrict__ starts, const int* __restrict__ blockSums,
    int* __restrict__ cursor)
{
    int i = blockIdx.x * 256 + threadIdx.x;
    if (i < N_NODES) {
        int v = starts[i] + blockSums[i >> 10];
        starts[i] = v;
        cursor[i] = v;
    }
}

__global__ __launch_bounds__(256) void scatter_kernel(
    const int* __restrict__ rows, const int* __restrict__ cols,
    int* __restrict__ cursor, int* __restrict__ csrCols)
{
    int e = blockIdx.x * 256 + threadIdx.x;
    if (e >= E_EDGES) return;
    int pos = atomicAdd(&cursor[rows[e]], 1);
    csrCols[pos] = cols[e];
}

// ---------------------------------------------------------------------------
// Kernel B: fused attention + aggregation, bf16-packed K/V, 2-edge unroll.
// ---------------------------------------------------------------------------
__global__ __launch_bounds__(256) void att_agg_kernel(
    const float* __restrict__ Q, const unsigned* __restrict__ KV,
    const float* __restrict__ filt,
    const int* __restrict__ starts, const int* __restrict__ counts,
    const int* __restrict__ csrCols,
    float* __restrict__ out)
{
    int t = threadIdx.x;
    int node = blockIdx.x * 2 + (t >> 7);
    if (node >= N_NODES) return;
    int d = t & 127;
    int h = d >> 5;

    float qd  = Q[(size_t)node * 128 + d];
    int   s   = starts[node];
    int   cnt = counts[node];

    float norm = 0.f, acc = 0.f;
    int i = 0;
    for (; i + 2 <= cnt; i += 2) {
        int c0 = csrCols[s + i];
        int c1 = csrCols[s + i + 1];
        unsigned kv0 = KV[(size_t)c0 * 128 + d];
        unsigned kv1 = KV[(size_t)c1 * 128 + d];
        float f0 = filt[(size_t)c0 * HEAD + h];
        float f1 = filt[(size_t)c1 * HEAD + h];
        float k0 = __uint_as_float(kv0 << 16);
        float v0 = __uint_as_float(kv0 & 0xffff0000u);
        float k1 = __uint_as_float(kv1 << 16);
        float v1 = __uint_as_float(kv1 & 0xffff0000u);

        float p0 = qd * k0;
        float p1 = qd * k1;
        p0 += __shfl_xor(p0, 1);   p1 += __shfl_xor(p1, 1);
        p0 += __shfl_xor(p0, 2);   p1 += __shfl_xor(p1, 2);
        p0 += __shfl_xor(p0, 4);   p1 += __shfl_xor(p1, 4);
        p0 += __shfl_xor(p0, 8);   p1 += __shfl_xor(p1, 8);
        p0 += __shfl_xor(p0, 16);  p1 += __shfl_xor(p1, 16);

        float w0 = __expf(fminf(fmaxf(p0, -10.f), 10.f) + f0);
        float w1 = __expf(fminf(fmaxf(p1, -10.f), 10.f) + f1);
        norm += w0 + w1;
        acc  += w0 * v0 + w1 * v1;
    }
    if (i < cnt) {
        int c0 = csrCols[s + i];
        unsigned kv0 = KV[(size_t)c0 * 128 + d];
        float f0 = filt[(size_t)c0 * HEAD + h];
        float k0 = __uint_as_float(kv0 << 16);
        float v0 = __uint_as_float(kv0 & 0xffff0000u);
        float p0 = qd * k0;
        p0 += __shfl_xor(p0, 1);
        p0 += __shfl_xor(p0, 2);
        p0 += __shfl_xor(p0, 4);
        p0 += __shfl_xor(p0, 8);
        p0 += __shfl_xor(p0, 16);
        float w0 = __expf(fminf(fmaxf(p0, -10.f), 10.f) + f0);
        norm += w0;
        acc  += w0 * v0;
    }
    out[(size_t)node * 128 + d] = acc / (norm + 1e-8f);
}

// ---------------------------------------------------------------------------
extern "C" void kernel_launch(void* const* d_in, const int* in_sizes, int n_in,
                              void* d_out, int out_size, void* d_ws, size_t ws_size,
                              hipStream_t stream) {
    const float* embeds = (const float*)d_in[0];
    const float* qT     = (const float*)d_in[1];
    const float* kT     = (const float*)d_in[2];
    const float* vT     = (const float*)d_in[3];
    const float* filt   = (const float*)d_in[4];
    const int*   rows   = (const int*)d_in[5];
    const int*   cols   = (const int*)d_in[6];
    float*       out    = (float*)d_out;

    // Workspace: Q: N*128 f32 | KV: N*128 u32 | counts,starts,cursor: N i32 |
    //            blockSums: 128 i32 | csrCols: E i32 | WtHi/WtLo: 3*128*128 u16
    float*    Q  = (float*)d_ws;
    unsigned* KV = (unsigned*)(Q + (size_t)N_NODES * 128);
    int* counts    = (int*)(KV + (size_t)N_NODES * 128);
    int* starts    = counts + N_NODES;
    int* cursor    = starts + N_NODES;
    int* blockSums = cursor + N_NODES;
    int* csrCols   = blockSums + 128;
    unsigned short* WtHi = (unsigned short*)(csrCols + E_EDGES);
    unsigned short* WtLo = WtHi + 3 * 128 * 128;

    hipMemsetAsync(counts, 0, sizeof(int) * N_NODES, stream);

    wsplit_kernel<<<48, 256, 0, stream>>>(qT, kT, vT, WtHi, WtLo);

    qkv_kernel<<<(N_NODES + 63) / 64, 256, 0, stream>>>(embeds, WtHi, WtLo, Q, KV);

    hist_kernel<<<(E_EDGES + 255) / 256, 256, 0, stream>>>(rows, counts);
    scan1_kernel<<<SCAN_NB, 256, 0, stream>>>(counts, starts, blockSums);
    scan2_kernel<<<1, 128, 0, stream>>>(blockSums);
    scan3_kernel<<<(N_NODES + 255) / 256, 256, 0, stream>>>(starts, blockSums, cursor);
    scatter_kernel<<<(E_EDGES + 255) / 256, 256, 0, stream>>>(rows, cols, cursor, csrCols);

    att_agg_kernel<<<(N_NODES + 1) / 2, 256, 0, stream>>>(
        Q, KV, filt, starts, counts, csrCols, out);
}